// Round 3
// baseline (779.183 us; speedup 1.0000x reference)
//
#include <hip/hip_runtime.h>
#include <stdint.h>

// ---------- types ----------
typedef __attribute__((ext_vector_type(8))) __bf16 bf16x8;
typedef __attribute__((ext_vector_type(4))) float f32x4;
typedef __attribute__((ext_vector_type(16))) float f32x16;

#define MIN_WF 0.001f
#define MIN_HF 0.001f
#define MIN_DF 0.001f
#define BN_INV 0.99999500003749977f /* 1/sqrt(1+1e-5) */

// async global->LDS, 16B per lane; LDS dest = wave-uniform base + lane*16
#define GLL(g, l)                                                              \
  __builtin_amdgcn_global_load_lds(                                            \
      (const __attribute__((address_space(1))) void*)(g),                      \
      (__attribute__((address_space(3))) void*)(l), 16, 0, 0)

__device__ __forceinline__ unsigned short f2bf(float f) {
  union { float f; unsigned int u; } v; v.f = f;
  unsigned int r = v.u + 0x7FFFu + ((v.u >> 16) & 1u);
  return (unsigned short)(r >> 16);
}

// ---------- cast/select even columns of x -> bf16 (Bc x 64) ----------
__global__ void cast_x_kernel(const float* __restrict__ x, unsigned short* __restrict__ xt) {
  int gid = blockIdx.x * blockDim.x + threadIdx.x; // 0 .. Bc*64
  int b = gid >> 6, i = gid & 63;
  xt[gid] = f2bf(x[(size_t)b * 128 + 2 * i]);
}

// ---------- transpose + cast: W (KxN f32, row-major) -> Wt (NxK bf16) ----------
__global__ void transpose_cast_kernel(const float* __restrict__ W, unsigned short* __restrict__ Wt,
                                      int K, int N) {
  __shared__ float tile[32][33];
  int tx = threadIdx.x & 31, ty = threadIdx.x >> 5; // 256 threads: ty 0..7
  int n0 = blockIdx.x * 32, k0 = blockIdx.y * 32;
#pragma unroll
  for (int i = 0; i < 32; i += 8)
    tile[ty + i][tx] = W[(size_t)(k0 + ty + i) * N + n0 + tx];
  __syncthreads();
#pragma unroll
  for (int i = 0; i < 32; i += 8)
    Wt[(size_t)(n0 + ty + i) * K + k0 + tx] = f2bf(tile[tx][ty + i]);
}

// ---------- 128x128 GEMM (kept for GEMM1, K=64) ----------
template <int EPI>
__global__ __launch_bounds__(256) void gemm_bt_kernel(
    const unsigned short* __restrict__ A, const unsigned short* __restrict__ Bt,
    const float* __restrict__ bias, const float* __restrict__ gamma,
    const float* __restrict__ beta, void* __restrict__ Cout,
    int M, int N, int K) {
  constexpr int BM = 128, BN = 128, BK = 32;
  __shared__ __align__(16) unsigned short As[2][BM * BK]; // 16 KB
  __shared__ __align__(16) unsigned short Bs[2][BN * BK]; // 16 KB
  int tid = threadIdx.x;
  int lane = tid & 63;
  int wave = tid >> 6;
  int wm = (wave & 1) * 64;
  int wn = (wave >> 1) * 64;
  int ml = lane & 15;
  int kq = lane >> 4;

  int L = blockIdx.x;
  int Nt = N >> 7;
  int Mt = M >> 7;
  int mt, nt;
  int Mloc = Mt >> 3;
  if (((Mt & 7) == 0) && ((Mloc & 3) == 0) && ((Nt & 3) == 0)) {
    int xcd = L & 7;
    int i = L >> 3;
    int Ng = Nt >> 2;
    int ln = i & 3;
    int lm = (i >> 2) & 3;
    int g = i >> 4;
    int gn = g % Ng;
    int gm = g / Ng;
    mt = xcd * Mloc + gm * 4 + lm;
    nt = gn * 4 + ln;
  } else {
    mt = L / Nt;
    nt = L % Nt;
  }
  size_t bm = (size_t)mt * BM;
  size_t bn = (size_t)nt * BN;

  int sr = lane >> 2;
  int sc = ((((lane & 3) + 4) - ((lane >> 3) & 3)) & 3) * 8;
  const unsigned short* gA = A + (bm + wave * 32 + sr) * (size_t)K + sc;
  const unsigned short* gB = Bt + (bn + wave * 32 + sr) * (size_t)K + sc;
  unsigned short* lA0 = As[0] + wave * 32 * BK;
  unsigned short* lA1 = As[1] + wave * 32 * BK;
  unsigned short* lB0 = Bs[0] + wave * 32 * BK;
  unsigned short* lB1 = Bs[1] + wave * 32 * BK;

  int kqs = ((kq + ((ml >> 1) & 3)) & 3) * 8;

  f32x4 zero = {0.f, 0.f, 0.f, 0.f};
  f32x4 acc[4][4];
#pragma unroll
  for (int i = 0; i < 4; i++)
#pragma unroll
    for (int j = 0; j < 4; j++) acc[i][j] = zero;

  for (int kb = 0; kb < K; kb += 64) {
    GLL(gA + kb, lA0);
    GLL(gA + kb + (size_t)16 * K, lA0 + 16 * BK);
    GLL(gA + kb + 32, lA1);
    GLL(gA + kb + 32 + (size_t)16 * K, lA1 + 16 * BK);
    GLL(gB + kb, lB0);
    GLL(gB + kb + (size_t)16 * K, lB0 + 16 * BK);
    GLL(gB + kb + 32, lB1);
    GLL(gB + kb + 32 + (size_t)16 * K, lB1 + 16 * BK);
    __syncthreads();

#pragma unroll
    for (int p = 0; p < 2; p++) {
      bf16x8 af[4], bfr[4];
#pragma unroll
      for (int i = 0; i < 4; i++)
        af[i] = *(const bf16x8*)(&As[p][(wm + i * 16 + ml) * BK + kqs]);
#pragma unroll
      for (int j = 0; j < 4; j++)
        bfr[j] = *(const bf16x8*)(&Bs[p][(wn + j * 16 + ml) * BK + kqs]);
#pragma unroll
      for (int i = 0; i < 4; i++)
#pragma unroll
        for (int j = 0; j < 4; j++)
          acc[i][j] = __builtin_amdgcn_mfma_f32_16x16x32_bf16(af[i], bfr[j], acc[i][j], 0, 0, 0);
    }
    __syncthreads();
  }

#pragma unroll
  for (int i = 0; i < 4; i++) {
#pragma unroll
    for (int j = 0; j < 4; j++) {
      size_t col = bn + wn + j * 16 + ml;
      float bv = bias[col];
      float gv = (EPI == 1) ? gamma[col] * BN_INV : 0.f;
      float bev = (EPI == 1) ? beta[col] : 0.f;
#pragma unroll
      for (int r = 0; r < 4; r++) {
        size_t row = bm + wm + i * 16 + kq * 4 + r;
        float v = acc[i][j][r] + bv;
        if (EPI == 1) {
          v = fmaxf(v, 0.f);
          v = gv * v + bev;
          ((unsigned short*)Cout)[row * (size_t)N + col] = f2bf(v);
        } else {
          ((float*)Cout)[row * (size_t)N + col] = v;
        }
      }
    }
  }
}

// ---------- 256x256 GEMM, 32x32x16 MFMA, K-step-split 8-phase schedule ----------
// BM=BN=256, BK=64/tile, 8 waves (2M x 4N), wave tile 128x64 = 4x2 C-tiles of
// 32x32. Iter = 2 K-tiles (t->buf0 @P1-4, t+1->buf1 @P5-8); each phase = ONE
// K=16 step over the whole wave tile: 6 ds_read_b128 (4 A + 2 B, consumed
// in-phase, zero re-reads) + 8 MFMA(32x32x16). Staging: P1:B(t+1)->buf1,
// P2:A(t+1)->buf1, P5:B(t+2)->buf0, P6:A(t+2)->buf0 (bufs written only in
// the half-iter where they're not read; barrier-separated). Gates vmcnt(0)
// at P4/P8 only -- every gated GLL has >=2-phase (~1100cyc) issue lead and
// nothing newer is in flight (counted-equivalent, never stalls fresh loads).
// LDS chunk swizzle: phys16Bchunk = logical ^ (row&7), via pre-swizzled
// global source (linear GLL dest) + same XOR on ds_read address.
template <int EPI>
__global__ __launch_bounds__(512, 2) void gemm256_kernel(
    const unsigned short* __restrict__ A, const unsigned short* __restrict__ Bt,
    const float* __restrict__ bias, const float* __restrict__ gamma,
    const float* __restrict__ beta, void* __restrict__ Cout,
    int M, int N, int K) {
  __shared__ __align__(16) unsigned short As[2][256 * 64]; // 64 KB
  __shared__ __align__(16) unsigned short Bs[2][256 * 64]; // 64 KB

  const int tid = threadIdx.x;
  const int lane = tid & 63;
  const int wave = tid >> 6; // 0..7
  const int wm = wave >> 2;  // 0..1 (M half: 128 rows)
  const int wn = wave & 3;   // 0..3 (N quarter: 64 cols)
  const int m32 = lane & 31;
  const int l5 = lane >> 5;  // 0..1 (k-subgroup)
  const int r7 = m32 & 7;

  int L = blockIdx.x;
  int Nt = N >> 8, Mt = M >> 8;
  int mt, nt;
  if ((Mt & 7) == 0) {
    int xcd = L & 7, ii = L >> 3, Mloc = Mt >> 3;
    mt = xcd * Mloc + (ii % Mloc);
    nt = ii / Mloc;
  } else {
    mt = L / Nt;
    nt = L % Nt;
  }
  const size_t bm = (size_t)mt << 8;
  const size_t bn = (size_t)nt << 8;
  const size_t rK = (size_t)K;

  // staging: per GLL a wave covers 8 rows x 128 B; phys chunk l&7 holds
  // logical chunk (l&7)^(row&7)  (pre-swizzled global source, linear dest).
  const int srow = lane >> 3;
  const int schk = (lane & 7) ^ srow;
  const unsigned short* gA = A + (bm + wave * 8 + srow) * rK + schk * 8;
  const unsigned short* gB = Bt + (bn + wave * 8 + srow) * rK + schk * 8;

#define LDSA(b, h, c) (&As[b][((h) * 128 + (c) * 64 + wave * 8) * 64])
#define LDSB(b, h, c) (&Bs[b][((h) * 128 + (c) * 64 + wave * 8) * 64])
#define STA(b, h, gp, t)                                                       \
  GLL((gp) + (size_t)((h) * 128) * rK + (t) * 64, LDSA(b, h, 0));              \
  GLL((gp) + (size_t)((h) * 128 + 64) * rK + (t) * 64, LDSA(b, h, 1))
#define STB(b, h, gp, t)                                                       \
  GLL((gp) + (size_t)((h) * 128) * rK + (t) * 64, LDSB(b, h, 0));              \
  GLL((gp) + (size_t)((h) * 128 + 64) * rK + (t) * 64, LDSB(b, h, 1))

  // fragment reads: A row = wm*128 + mi*32 + m32 ; B row = wn*64 + ni*32 + m32.
  // row&7 == m32&7 for all mi/ni (offsets are multiples of 32).
  // k element offset for K-step ks: chunk = ks*2 + l5 (8 elems each),
  // physical chunk = chunk ^ (row&7).
  const unsigned short* rA[2] = {&As[0][(wm * 128 + m32) * 64],
                                 &As[1][(wm * 128 + m32) * 64]};
  const unsigned short* rB[2] = {&Bs[0][(wn * 64 + m32) * 64],
                                 &Bs[1][(wn * 64 + m32) * 64]};

  f32x16 acc[4][2];
#pragma unroll
  for (int mi = 0; mi < 4; mi++)
#pragma unroll
    for (int ni = 0; ni < 2; ni++)
#pragma unroll
      for (int r = 0; r < 16; r++) acc[mi][ni][r] = 0.f;

#define PHASE(bsel, ks, STAGE, GATE)                                           \
  {                                                                            \
    bf16x8 afr[4], bqr[2];                                                     \
    STAGE;                                                                     \
    {                                                                          \
      const int ko = (((ks) * 2 + l5) ^ r7) * 8;                               \
      _Pragma("unroll") for (int mi = 0; mi < 4; mi++)                         \
          afr[mi] = *(const bf16x8*)(rA[bsel] + mi * 2048 + ko);               \
      _Pragma("unroll") for (int ni = 0; ni < 2; ni++)                         \
          bqr[ni] = *(const bf16x8*)(rB[bsel] + ni * 2048 + ko);               \
    }                                                                          \
    __builtin_amdgcn_s_setprio(1);                                             \
    _Pragma("unroll") for (int mi = 0; mi < 4; mi++)                           \
        _Pragma("unroll") for (int ni = 0; ni < 2; ni++)                       \
            acc[mi][ni] = __builtin_amdgcn_mfma_f32_32x32x16_bf16(             \
                afr[mi], bqr[ni], acc[mi][ni], 0, 0, 0);                       \
    __builtin_amdgcn_s_setprio(0);                                             \
    __builtin_amdgcn_sched_barrier(0);                                         \
    GATE;                                                                      \
    __builtin_amdgcn_s_barrier();                                              \
    asm volatile("" ::: "memory");                                             \
  }
#define GATE0 asm volatile("s_waitcnt vmcnt(0)" ::: "memory")
#define NOP do {} while (0)

  const int NT = K >> 6;   // 64-wide K tiles (even, >=2)
  const int NIT = NT >> 1; // iterations (2 tiles each)

  // prologue: tile0 -> buf0 (8 GLL), drain, barrier.
  STB(0, 0, gB, 0);
  STB(0, 1, gB, 0);
  STA(0, 0, gA, 0);
  STA(0, 1, gA, 0);
  GATE0;
  __builtin_amdgcn_s_barrier();
  asm volatile("" ::: "memory");

  const unsigned short* gAi = gA;
  const unsigned short* gBi = gB;

#define ITER_BODY(LAST)                                                        \
  {                                                                            \
    PHASE(0, 0, { STB(1, 0, gBi, 1); STB(1, 1, gBi, 1); }, NOP);               \
    PHASE(0, 1, { STA(1, 0, gAi, 1); STA(1, 1, gAi, 1); }, NOP);               \
    PHASE(0, 2, NOP, NOP);                                                     \
    PHASE(0, 3, NOP, GATE0);                                                   \
    PHASE(1, 0, { if (!(LAST)) { STB(0, 0, gBi, 2); STB(0, 1, gBi, 2); } }, NOP); \
    PHASE(1, 1, { if (!(LAST)) { STA(0, 0, gAi, 2); STA(0, 1, gAi, 2); } }, NOP); \
    PHASE(1, 2, NOP, NOP);                                                     \
    PHASE(1, 3, NOP, GATE0);                                                   \
  }

  for (int it = 0; it < NIT - 1; ++it) {
    ITER_BODY(0);
    gAi += 128;
    gBi += 128;
  }
  ITER_BODY(1);

  // epilogue. 32x32 D mapping: col = lane&31, row = (r&3) + 8*(r>>2) + 4*(lane>>5)
#pragma unroll
  for (int ni = 0; ni < 2; ni++) {
    const size_t col = bn + wn * 64 + ni * 32 + m32;
    const float bv = bias[col];
    const float gv = (EPI == 1) ? gamma[col] * BN_INV : 0.f;
    const float bev = (EPI == 1) ? beta[col] : 0.f;
#pragma unroll
    for (int mi = 0; mi < 4; mi++) {
#pragma unroll
      for (int r = 0; r < 16; r++) {
        const size_t row = bm + wm * 128 + mi * 32 + (r & 3) + ((r >> 2) * 8) + l5 * 4;
        float v = acc[mi][ni][r] + bv;
        if (EPI == 1) {
          v = fmaxf(v, 0.f);
          v = gv * v + bev;
          ((unsigned short*)Cout)[row * (size_t)N + col] = f2bf(v);
        } else {
          ((float*)Cout)[row * (size_t)N + col] = v;
        }
      }
    }
  }
#undef ITER_BODY
#undef NOP
#undef GATE0
#undef PHASE
#undef STB
#undef STA
#undef LDSB
#undef LDSA
}

// ---------- RQ spline + output assembly + log_det ----------
__global__ void spline_kernel(const float* __restrict__ x, const float* __restrict__ params,
                              float* __restrict__ out, float* __restrict__ logdet) {
  int gid = blockIdx.x * blockDim.x + threadIdx.x; // 0 .. Bc*64
  int b = gid >> 6;
  int i = gid & 63;

  const float4* p = (const float4*)(params + (size_t)gid * 24);
  float4 q0 = p[0], q1 = p[1], q2 = p[2], q3 = p[3], q4 = p[4], q5 = p[5];
  float w[8] = {q0.x, q0.y, q0.z, q0.w, q1.x, q1.y, q1.z, q1.w};
  float hh[8] = {q2.x, q2.y, q2.z, q2.w, q3.x, q3.y, q3.z, q3.w};
  float dv[8] = {q4.x, q4.y, q4.z, q4.w, q5.x, q5.y, q5.z, q5.w};

  float mx = w[0];
#pragma unroll
  for (int k = 1; k < 8; k++) mx = fmaxf(mx, w[k]);
  float s = 0.f;
#pragma unroll
  for (int k = 0; k < 8; k++) { w[k] = expf(w[k] - mx); s += w[k]; }
  float sc = (1.f - 8.f * MIN_WF) / s;
  float cw[9];
  cw[0] = 0.f;
#pragma unroll
  for (int k = 0; k < 8; k++) cw[k + 1] = cw[k] + (MIN_WF + sc * w[k]);

  float mh = hh[0];
#pragma unroll
  for (int k = 1; k < 8; k++) mh = fmaxf(mh, hh[k]);
  float sh = 0.f;
#pragma unroll
  for (int k = 0; k < 8; k++) { hh[k] = expf(hh[k] - mh); sh += hh[k]; }
  float sch = (1.f - 8.f * MIN_HF) / sh;
  float ch[9];
  ch[0] = 0.f;
#pragma unroll
  for (int k = 0; k < 8; k++) ch[k + 1] = ch[k] + (MIN_HF + sch * hh[k]);

  float dk[9];
#pragma unroll
  for (int k = 0; k < 8; k++)
    dk[k] = MIN_DF + (fmaxf(dv[k], 0.f) + log1pf(expf(-fabsf(dv[k]))));
  dk[8] = MIN_DF;

  float xv = x[(size_t)b * 128 + 2 * i + 1]; // identity (odd) column

  int bi = 0;
#pragma unroll
  for (int k = 0; k < 8; k++) bi += (xv > cw[k]) ? 1 : 0;
  bi = (bi > 7) ? 7 : bi;

  float xl = 0.f, xr = 0.f, yl = 0.f, yr = 0.f, dl = 0.f, dr = 0.f;
#pragma unroll
  for (int k = 0; k < 8; k++) {
    if (k == bi) {
      xl = cw[k]; xr = cw[k + 1];
      yl = ch[k]; yr = ch[k + 1];
      dl = dk[k]; dr = dk[k + 1];
    }
  }

  float bw = xr - xl, bh = yr - yl;
  float t = (xv - xl) / bw;
  t = fminf(fmaxf(t, 0.f), 1.f);
  float num = bh * (dl * t * t + 2.f * t * (1.f - t));
  float den = dl + (dr - dl) * t;
  float o = yl + num / den;
  float ld = logf(bh) + 2.f * logf(2.f * t * (1.f - t) * dr + dl) - logf(den);

  float xe = x[(size_t)b * 128 + 2 * i]; // transform (even) column passthrough
  ((float2*)out)[(size_t)b * 64 + i] = make_float2(xe, o);

#pragma unroll
  for (int off = 32; off > 0; off >>= 1) ld += __shfl_xor(ld, off, 64);
  if ((threadIdx.x & 63) == 0) logdet[b] = ld;
}

// ---------- launch ----------
extern "C" void kernel_launch(void* const* d_in, const int* in_sizes, int n_in,
                              void* d_out, int out_size, void* d_ws, size_t ws_size,
                              hipStream_t stream) {
  const float* x   = (const float*)d_in[0];
  const float* W1  = (const float*)d_in[1];
  const float* b1  = (const float*)d_in[2];
  const float* g1  = (const float*)d_in[3];
  const float* be1 = (const float*)d_in[4];
  const float* W2  = (const float*)d_in[5];
  const float* b2  = (const float*)d_in[6];
  const float* g2  = (const float*)d_in[7];
  const float* be2 = (const float*)d_in[8];
  const float* W3  = (const float*)d_in[9];
  const float* b3  = (const float*)d_in[10];

  const int B = 32768, H = 2048, DOUT = 1536;

  // ---- workspace layout (chunked) ----
  // persistent weights: W1t 262,144 + W2t 8,388,608 + W3t 6,291,456 = 14,942,208 B
  // per chunk of Bc rows: xt 128*Bc + h2 4096*Bc + max(h1 4096*Bc, params 6144*Bc)
  const size_t WEIGHTS = 14942208;
  int Bc = 1024;
  {
    const int cand[5] = {32768, 16384, 8192, 4096, 2048};
    for (int c = 0; c < 5; c++) {
      size_t need = WEIGHTS + (size_t)10368 * cand[c];
      if (need <= ws_size) { Bc = cand[c]; break; }
    }
  }
  char* ws = (char*)d_ws;
  unsigned short* W1t = (unsigned short*)(ws + 0);
  unsigned short* W2t = (unsigned short*)(ws + 262144);
  unsigned short* W3t = (unsigned short*)(ws + 8650752);
  unsigned short* xt  = (unsigned short*)(ws + WEIGHTS);
  unsigned short* h2  = (unsigned short*)(ws + WEIGHTS + (size_t)128 * Bc);
  char*           uni = ws + WEIGHTS + (size_t)(128 + 4096) * Bc;
  unsigned short* h1  = (unsigned short*)uni;
  float*      params  = (float*)uni; // aliases h1 (dead when GEMM3 writes)

  float* out = (float*)d_out;
  float* logdet = out + (size_t)B * 128;

  transpose_cast_kernel<<<dim3(64, 2), dim3(256), 0, stream>>>(W1, W1t, 64, H);
  transpose_cast_kernel<<<dim3(64, 64), dim3(256), 0, stream>>>(W2, W2t, H, H);
  transpose_cast_kernel<<<dim3(48, 64), dim3(256), 0, stream>>>(W3, W3t, H, DOUT);

  for (int r0 = 0; r0 < B; r0 += Bc) {
    cast_x_kernel<<<dim3(Bc / 4), dim3(256), 0, stream>>>(x + (size_t)r0 * 128, xt);
    // GEMM1: K=64 -> 128^2 kernel (memory-bound)
    gemm_bt_kernel<1><<<dim3((Bc / 128) * 16), dim3(256), 0, stream>>>(
        xt, W1t, b1, g1, be1, (void*)h1, Bc, H, 64);
    // GEMM2/GEMM3: 256^2 32x32-MFMA K-step-split 8-phase schedule
    gemm256_kernel<1><<<dim3((Bc / 256) * (H / 256)), dim3(512), 0, stream>>>(
        h1, W2t, b2, g2, be2, (void*)h2, Bc, H, H);
    gemm256_kernel<0><<<dim3((Bc / 256) * (DOUT / 256)), dim3(512), 0, stream>>>(
        h2, W3t, b3, b3, b3, (void*)params, Bc, DOUT, H);
    spline_kernel<<<dim3(Bc / 4), dim3(256), 0, stream>>>(
        x + (size_t)r0 * 128, params, out + (size_t)r0 * 128, logdet + r0);
  }
}

// Round 4
// 728.189 us; speedup vs baseline: 1.0700x; 1.0700x over previous
//
#include <hip/hip_runtime.h>
#include <stdint.h>

// ---------- types ----------
typedef __attribute__((ext_vector_type(8))) __bf16 bf16x8;
typedef __attribute__((ext_vector_type(4))) float f32x4;

#define MIN_WF 0.001f
#define MIN_HF 0.001f
#define MIN_DF 0.001f
#define BN_INV 0.99999500003749977f /* 1/sqrt(1+1e-5) */

// async global->LDS, 16B per lane; LDS dest = wave-uniform base + lane*16
#define GLL(g, l)                                                              \
  __builtin_amdgcn_global_load_lds(                                            \
      (const __attribute__((address_space(1))) void*)(g),                      \
      (__attribute__((address_space(3))) void*)(l), 16, 0, 0)

__device__ __forceinline__ unsigned short f2bf(float f) {
  union { float f; unsigned int u; } v; v.f = f;
  unsigned int r = v.u + 0x7FFFu + ((v.u >> 16) & 1u);
  return (unsigned short)(r >> 16);
}

// ---------- cast/select even columns of x -> bf16 (Bc x 64) ----------
__global__ void cast_x_kernel(const float* __restrict__ x, unsigned short* __restrict__ xt) {
  int gid = blockIdx.x * blockDim.x + threadIdx.x; // 0 .. Bc*64
  int b = gid >> 6, i = gid & 63;
  xt[gid] = f2bf(x[(size_t)b * 128 + 2 * i]);
}

// ---------- transpose + cast: W (KxN f32, row-major) -> Wt (NxK bf16) ----------
__global__ void transpose_cast_kernel(const float* __restrict__ W, unsigned short* __restrict__ Wt,
                                      int K, int N) {
  __shared__ float tile[32][33];
  int tx = threadIdx.x & 31, ty = threadIdx.x >> 5; // 256 threads: ty 0..7
  int n0 = blockIdx.x * 32, k0 = blockIdx.y * 32;
#pragma unroll
  for (int i = 0; i < 32; i += 8)
    tile[ty + i][tx] = W[(size_t)(k0 + ty + i) * N + n0 + tx];
  __syncthreads();
#pragma unroll
  for (int i = 0; i < 32; i += 8)
    Wt[(size_t)(n0 + ty + i) * K + k0 + tx] = f2bf(tile[tx][ty + i]);
}

// ---------- 128x128 GEMM (kept for GEMM1, K=64) ----------
template <int EPI>
__global__ __launch_bounds__(256) void gemm_bt_kernel(
    const unsigned short* __restrict__ A, const unsigned short* __restrict__ Bt,
    const float* __restrict__ bias, const float* __restrict__ gamma,
    const float* __restrict__ beta, void* __restrict__ Cout,
    int M, int N, int K) {
  constexpr int BM = 128, BN = 128, BK = 32;
  __shared__ __align__(16) unsigned short As[2][BM * BK]; // 16 KB
  __shared__ __align__(16) unsigned short Bs[2][BN * BK]; // 16 KB
  int tid = threadIdx.x;
  int lane = tid & 63;
  int wave = tid >> 6;
  int wm = (wave & 1) * 64;
  int wn = (wave >> 1) * 64;
  int ml = lane & 15;
  int kq = lane >> 4;

  int L = blockIdx.x;
  int Nt = N >> 7;
  int Mt = M >> 7;
  int mt, nt;
  int Mloc = Mt >> 3;
  if (((Mt & 7) == 0) && ((Mloc & 3) == 0) && ((Nt & 3) == 0)) {
    int xcd = L & 7;
    int i = L >> 3;
    int Ng = Nt >> 2;
    int ln = i & 3;
    int lm = (i >> 2) & 3;
    int g = i >> 4;
    int gn = g % Ng;
    int gm = g / Ng;
    mt = xcd * Mloc + gm * 4 + lm;
    nt = gn * 4 + ln;
  } else {
    mt = L / Nt;
    nt = L % Nt;
  }
  size_t bm = (size_t)mt * BM;
  size_t bn = (size_t)nt * BN;

  int sr = lane >> 2;
  int sc = ((((lane & 3) + 4) - ((lane >> 3) & 3)) & 3) * 8;
  const unsigned short* gA = A + (bm + wave * 32 + sr) * (size_t)K + sc;
  const unsigned short* gB = Bt + (bn + wave * 32 + sr) * (size_t)K + sc;
  unsigned short* lA0 = As[0] + wave * 32 * BK;
  unsigned short* lA1 = As[1] + wave * 32 * BK;
  unsigned short* lB0 = Bs[0] + wave * 32 * BK;
  unsigned short* lB1 = Bs[1] + wave * 32 * BK;

  int kqs = ((kq + ((ml >> 1) & 3)) & 3) * 8;

  f32x4 zero = {0.f, 0.f, 0.f, 0.f};
  f32x4 acc[4][4];
#pragma unroll
  for (int i = 0; i < 4; i++)
#pragma unroll
    for (int j = 0; j < 4; j++) acc[i][j] = zero;

  for (int kb = 0; kb < K; kb += 64) {
    GLL(gA + kb, lA0);
    GLL(gA + kb + (size_t)16 * K, lA0 + 16 * BK);
    GLL(gA + kb + 32, lA1);
    GLL(gA + kb + 32 + (size_t)16 * K, lA1 + 16 * BK);
    GLL(gB + kb, lB0);
    GLL(gB + kb + (size_t)16 * K, lB0 + 16 * BK);
    GLL(gB + kb + 32, lB1);
    GLL(gB + kb + 32 + (size_t)16 * K, lB1 + 16 * BK);
    __syncthreads();

#pragma unroll
    for (int p = 0; p < 2; p++) {
      bf16x8 af[4], bfr[4];
#pragma unroll
      for (int i = 0; i < 4; i++)
        af[i] = *(const bf16x8*)(&As[p][(wm + i * 16 + ml) * BK + kqs]);
#pragma unroll
      for (int j = 0; j < 4; j++)
        bfr[j] = *(const bf16x8*)(&Bs[p][(wn + j * 16 + ml) * BK + kqs]);
#pragma unroll
      for (int i = 0; i < 4; i++)
#pragma unroll
        for (int j = 0; j < 4; j++)
          acc[i][j] = __builtin_amdgcn_mfma_f32_16x16x32_bf16(af[i], bfr[j], acc[i][j], 0, 0, 0);
    }
    __syncthreads();
  }

#pragma unroll
  for (int i = 0; i < 4; i++) {
#pragma unroll
    for (int j = 0; j < 4; j++) {
      size_t col = bn + wn + j * 16 + ml;
      float bv = bias[col];
      float gv = (EPI == 1) ? gamma[col] * BN_INV : 0.f;
      float bev = (EPI == 1) ? beta[col] : 0.f;
#pragma unroll
      for (int r = 0; r < 4; r++) {
        size_t row = bm + wm + i * 16 + kq * 4 + r;
        float v = acc[i][j][r] + bv;
        if (EPI == 1) {
          v = fmaxf(v, 0.f);
          v = gv * v + bev;
          ((unsigned short*)Cout)[row * (size_t)N + col] = f2bf(v);
        } else {
          ((float*)Cout)[row * (size_t)N + col] = v;
        }
      }
    }
  }
}

// ---------- 256x256 GEMM, 16x16x32 MFMA, B-carry snake + uniform staging ----
// BM=BN=256, BK=64/tile, 8 waves (2M x 4N), wave tile 128x64, 128 KiB LDS.
// Iter = 2 K-tiles (t->buf0 @P1-4, t+1->buf1 @P5-8). Quadrant order per
// K-tile (B-carry): P1 a03xb01 (12 ds_reads), P2 a03xb23 (4), P3 a47xb23
// (8), P4 a47xb01 (0 reads -- pure-reg MFMA absorbs the vmcnt gate).
// No re-reads: 48 ds_read_b128/wave/iter (was 64). Deadness: B(buf) dead
// after P2, A(buf) dead after P3 (register carry; reads drain before their
// consuming MFMA, which precedes the phase-end barrier).
// Staging stream, uniform 1 half-tile (2 GLL)/phase:
//   P1: A0(t+1)->buf1   P2: A1(t+1)->buf1   (buf1-A dead since prev P7)
//   P3: B0(t+2)->buf0   P4: B1(t+2)->buf0   (buf0-B dead after P2)
//   P5: A0(t+2)->buf0   P6: A1(t+2)->buf0   (buf0-A dead after P3)
//   P7: B0(t+3)->buf1   P8: B1(t+3)->buf1   (buf1-B dead after P6)
// Gates vmcnt(4) at P4 (guards buf1 = tile t+1) and P8 (guards buf0 =
// tile t+2): 12 outstanding pre-gate, waits oldest 8, always leaves the
// newest B pair in flight. A-loads get >=2-phase lead, B-loads 4-6.
// Last iter: stages suppressed, gates vmcnt(0).
template <int EPI>
__global__ __launch_bounds__(512, 2) void gemm256_kernel(
    const unsigned short* __restrict__ A, const unsigned short* __restrict__ Bt,
    const float* __restrict__ bias, const float* __restrict__ gamma,
    const float* __restrict__ beta, void* __restrict__ Cout,
    int M, int N, int K) {
  __shared__ __align__(16) unsigned short As[2][256 * 64]; // 64 KB
  __shared__ __align__(16) unsigned short Bs[2][256 * 64]; // 64 KB

  const int tid = threadIdx.x;
  const int lane = tid & 63;
  const int wave = tid >> 6; // 0..7
  const int wm = wave >> 2;  // 0..1 (M half)
  const int wn = wave & 3;   // 0..3 (N quarter)
  const int ml = lane & 15;
  const int kq = lane >> 4;  // 0..3

  int L = blockIdx.x;
  int Nt = N >> 8, Mt = M >> 8;
  int mt, nt;
  if ((Mt & 7) == 0) {
    int xcd = L & 7, ii = L >> 3, Mloc = Mt >> 3;
    mt = xcd * Mloc + (ii % Mloc);
    nt = ii / Mloc;
  } else {
    mt = L / Nt;
    nt = L % Nt;
  }
  const size_t bm = (size_t)mt << 8;
  const size_t bn = (size_t)nt << 8;
  const size_t rK = (size_t)K;

  // staging: per GLL a wave covers 8 rows x 128 B; phys chunk l&7 holds
  // logical chunk (l&7)^(row&7)  (pre-swizzled global source, linear dest).
  const int srow = lane >> 3;
  const int schk = (lane & 7) ^ srow;
  const unsigned short* gA = A + (bm + wave * 8 + srow) * rK + schk * 8;
  const unsigned short* gB = Bt + (bn + wave * 8 + srow) * rK + schk * 8;

#define LDSA(b, h, c) (&As[b][((h) * 128 + (c) * 64 + wave * 8) * 64])
#define LDSB(b, h, c) (&Bs[b][((h) * 128 + (c) * 64 + wave * 8) * 64])
#define STA(b, h, gp, t)                                                       \
  GLL((gp) + (size_t)((h) * 128) * rK + (t) * 64, LDSA(b, h, 0));              \
  GLL((gp) + (size_t)((h) * 128 + 64) * rK + (t) * 64, LDSA(b, h, 1))
#define STB(b, h, gp, t)                                                       \
  GLL((gp) + (size_t)((h) * 128) * rK + (t) * 64, LDSB(b, h, 0));              \
  GLL((gp) + (size_t)((h) * 128 + 64) * rK + (t) * 64, LDSB(b, h, 1))

  // fragment-read bases; row&7 == ml&7 for both A and B reads.
  const unsigned short* rA[2] = {&As[0][(wm * 128 + ml) * 64],
                                 &As[1][(wm * 128 + ml) * 64]};
  const unsigned short* rB[2] = {&Bs[0][(wn * 64 + ml) * 64],
                                 &Bs[1][(wn * 64 + ml) * 64]};
  const int ks0 = ((kq) ^ (ml & 7)) * 8;       // K-plane 0
  const int ks1 = ((4 + kq) ^ (ml & 7)) * 8;   // K-plane 1

  f32x4 acc[8][4];
  f32x4 zero = {0.f, 0.f, 0.f, 0.f};
#pragma unroll
  for (int i = 0; i < 8; i++)
#pragma unroll
    for (int j = 0; j < 4; j++) acc[i][j] = zero;

#define LD_A4(dst, b, ibase)                                                   \
  {                                                                            \
    _Pragma("unroll") for (int q = 0; q < 4; q++) {                            \
      dst[q][0] = *(const bf16x8*)(rA[b] + ((ibase) + q) * 1024 + ks0);        \
      dst[q][1] = *(const bf16x8*)(rA[b] + ((ibase) + q) * 1024 + ks1);        \
    }                                                                          \
  }
#define LD_B2(dst, b, jbase)                                                   \
  {                                                                            \
    _Pragma("unroll") for (int q = 0; q < 2; q++) {                            \
      dst[q][0] = *(const bf16x8*)(rB[b] + ((jbase) + q) * 1024 + ks0);        \
      dst[q][1] = *(const bf16x8*)(rB[b] + ((jbase) + q) * 1024 + ks1);        \
    }                                                                          \
  }
#define MMA16(aarr, barr, ig, jg)                                              \
  {                                                                            \
    _Pragma("unroll") for (int q = 0; q < 4; q++)                              \
        _Pragma("unroll") for (int r = 0; r < 2; r++) {                        \
      acc[(ig) * 4 + q][(jg) * 2 + r] = __builtin_amdgcn_mfma_f32_16x16x32_bf16( \
          aarr[q][0], barr[r][0], acc[(ig) * 4 + q][(jg) * 2 + r], 0, 0, 0);   \
      acc[(ig) * 4 + q][(jg) * 2 + r] = __builtin_amdgcn_mfma_f32_16x16x32_bf16( \
          aarr[q][1], barr[r][1], acc[(ig) * 4 + q][(jg) * 2 + r], 0, 0, 0);   \
    }                                                                          \
  }
#define FENCE asm volatile("" ::: "memory")
#define PH_BAR                                                                 \
  __builtin_amdgcn_sched_barrier(0);                                           \
  __builtin_amdgcn_s_barrier();                                                \
  FENCE
#define GATE4 asm volatile("s_waitcnt vmcnt(4)" ::: "memory")
#define GATE0 asm volatile("s_waitcnt vmcnt(0)" ::: "memory")

  // One K-tile = 4 phases, B-carry quadrant snake. SGn = staging for phase n.
#define KT(bsel, SG1, SG2, SG3, SG4, GATE)                                     \
  {                                                                            \
    bf16x8 a03[4][2], a47[4][2], b01[2][2], b23[2][2];                         \
    /* P1: a03 x b01 (12 reads) */                                             \
    SG1;                                                                       \
    LD_A4(a03, bsel, 0);                                                       \
    LD_B2(b01, bsel, 0);                                                       \
    __builtin_amdgcn_s_setprio(1);                                             \
    MMA16(a03, b01, 0, 0);                                                     \
    __builtin_amdgcn_s_setprio(0);                                             \
    PH_BAR;                                                                    \
    /* P2: a03 x b23 (4 reads); B(buf) dead after this phase */                \
    SG2;                                                                       \
    LD_B2(b23, bsel, 2);                                                       \
    __builtin_amdgcn_s_setprio(1);                                             \
    MMA16(a03, b23, 0, 1);                                                     \
    __builtin_amdgcn_s_setprio(0);                                             \
    PH_BAR;                                                                    \
    /* P3: a47 x b23 (8 reads); A(buf) dead after this phase */                \
    SG3;                                                                       \
    LD_A4(a47, bsel, 4);                                                       \
    __builtin_amdgcn_s_setprio(1);                                             \
    MMA16(a47, b23, 1, 1);                                                     \
    __builtin_amdgcn_s_setprio(0);                                             \
    PH_BAR;                                                                    \
    /* P4: a47 x b01 (0 reads, pure-reg); gate lives here */                   \
    SG4;                                                                       \
    __builtin_amdgcn_s_setprio(1);                                             \
    MMA16(a47, b01, 1, 0);                                                     \
    __builtin_amdgcn_s_setprio(0);                                             \
    __builtin_amdgcn_sched_barrier(0);                                         \
    GATE;                                                                      \
    __builtin_amdgcn_s_barrier();                                              \
    FENCE;                                                                     \
  }

  const int NT = K >> 6;   // 64-wide K tiles (even, >=2)
  const int NIT = NT >> 1; // iterations (2 tiles each)

  // prologue: tile0 (8 GLL) + B(tile1) (4 GLL); gate leaves B(1) in flight.
  STA(0, 0, gA, 0);
  STA(0, 1, gA, 0);
  STB(0, 0, gB, 0);
  STB(0, 1, gB, 0);
  STB(1, 0, gB, 1);
  STB(1, 1, gB, 1);
  GATE4;
  __builtin_amdgcn_s_barrier();
  FENCE;

  const unsigned short* gAi = gA;
  const unsigned short* gBi = gB;

#define ITER_BODY(LAST)                                                        \
  {                                                                            \
    KT(0,                                                                      \
       { STA(1, 0, gAi, 1); },                                                 \
       { STA(1, 1, gAi, 1); },                                                 \
       { if (!(LAST)) { STB(0, 0, gBi, 2); } },                                \
       { if (!(LAST)) { STB(0, 1, gBi, 2); } },                                \
       { if (LAST) { GATE0; } else { GATE4; } });                              \
    KT(1,                                                                      \
       { if (!(LAST)) { STA(0, 0, gAi, 2); } },                                \
       { if (!(LAST)) { STA(0, 1, gAi, 2); } },                                \
       { if (!(LAST)) { STB(1, 0, gBi, 3); } },                                \
       { if (!(LAST)) { STB(1, 1, gBi, 3); } },                                \
       { if (LAST) { GATE0; } else { GATE4; } });                              \
  }

  for (int it = 0; it < NIT - 1; ++it) {
    ITER_BODY(0);
    gAi += 128;
    gBi += 128;
  }
  ITER_BODY(1);

  // epilogue. D mapping: col = lane&15, row = (lane>>4)*4 + r
#pragma unroll
  for (int j = 0; j < 4; j++) {
    const size_t col = bn + wn * 64 + j * 16 + ml;
    const float bv = bias[col];
    const float gv = (EPI == 1) ? gamma[col] * BN_INV : 0.f;
    const float bev = (EPI == 1) ? beta[col] : 0.f;
#pragma unroll
    for (int i = 0; i < 8; i++) {
      const size_t row0 = bm + wm * 128 + i * 16 + kq * 4;
#pragma unroll
      for (int r = 0; r < 4; r++) {
        float v = acc[i][j][r] + bv;
        if (EPI == 1) {
          v = fmaxf(v, 0.f);
          v = gv * v + bev;
          ((unsigned short*)Cout)[(row0 + r) * (size_t)N + col] = f2bf(v);
        } else {
          ((float*)Cout)[(row0 + r) * (size_t)N + col] = v;
        }
      }
    }
  }
#undef ITER_BODY
#undef KT
#undef GATE0
#undef GATE4
#undef PH_BAR
#undef FENCE
#undef MMA16
#undef LD_B2
#undef LD_A4
#undef STB
#undef STA
#undef LDSB
#undef LDSA
}

// ---------- RQ spline + output assembly + log_det ----------
__global__ void spline_kernel(const float* __restrict__ x, const float* __restrict__ params,
                              float* __restrict__ out, float* __restrict__ logdet) {
  int gid = blockIdx.x * blockDim.x + threadIdx.x; // 0 .. Bc*64
  int b = gid >> 6;
  int i = gid & 63;

  const float4* p = (const float4*)(params + (size_t)gid * 24);
  float4 q0 = p[0], q1 = p[1], q2 = p[2], q3 = p[3], q4 = p[4], q5 = p[5];
  float w[8] = {q0.x, q0.y, q0.z, q0.w, q1.x, q1.y, q1.z, q1.w};
  float hh[8] = {q2.x, q2.y, q2.z, q2.w, q3.x, q3.y, q3.z, q3.w};
  float dv[8] = {q4.x, q4.y, q4.z, q4.w, q5.x, q5.y, q5.z, q5.w};

  float mx = w[0];
#pragma unroll
  for (int k = 1; k < 8; k++) mx = fmaxf(mx, w[k]);
  float s = 0.f;
#pragma unroll
  for (int k = 0; k < 8; k++) { w[k] = expf(w[k] - mx); s += w[k]; }
  float sc = (1.f - 8.f * MIN_WF) / s;
  float cw[9];
  cw[0] = 0.f;
#pragma unroll
  for (int k = 0; k < 8; k++) cw[k + 1] = cw[k] + (MIN_WF + sc * w[k]);

  float mh = hh[0];
#pragma unroll
  for (int k = 1; k < 8; k++) mh = fmaxf(mh, hh[k]);
  float sh = 0.f;
#pragma unroll
  for (int k = 0; k < 8; k++) { hh[k] = expf(hh[k] - mh); sh += hh[k]; }
  float sch = (1.f - 8.f * MIN_HF) / sh;
  float ch[9];
  ch[0] = 0.f;
#pragma unroll
  for (int k = 0; k < 8; k++) ch[k + 1] = ch[k] + (MIN_HF + sch * hh[k]);

  float dk[9];
#pragma unroll
  for (int k = 0; k < 8; k++)
    dk[k] = MIN_DF + (fmaxf(dv[k], 0.f) + log1pf(expf(-fabsf(dv[k]))));
  dk[8] = MIN_DF;

  float xv = x[(size_t)b * 128 + 2 * i + 1]; // identity (odd) column

  int bi = 0;
#pragma unroll
  for (int k = 0; k < 8; k++) bi += (xv > cw[k]) ? 1 : 0;
  bi = (bi > 7) ? 7 : bi;

  float xl = 0.f, xr = 0.f, yl = 0.f, yr = 0.f, dl = 0.f, dr = 0.f;
#pragma unroll
  for (int k = 0; k < 8; k++) {
    if (k == bi) {
      xl = cw[k]; xr = cw[k + 1];
      yl = ch[k]; yr = ch[k + 1];
      dl = dk[k]; dr = dk[k + 1];
    }
  }

  float bw = xr - xl, bh = yr - yl;
  float t = (xv - xl) / bw;
  t = fminf(fmaxf(t, 0.f), 1.f);
  float num = bh * (dl * t * t + 2.f * t * (1.f - t));
  float den = dl + (dr - dl) * t;
  float o = yl + num / den;
  float ld = logf(bh) + 2.f * logf(2.f * t * (1.f - t) * dr + dl) - logf(den);

  float xe = x[(size_t)b * 128 + 2 * i]; // transform (even) column passthrough
  ((float2*)out)[(size_t)b * 64 + i] = make_float2(xe, o);

#pragma unroll
  for (int off = 32; off > 0; off >>= 1) ld += __shfl_xor(ld, off, 64);
  if ((threadIdx.x & 63) == 0) logdet[b] = ld;
}

// ---------- launch ----------
extern "C" void kernel_launch(void* const* d_in, const int* in_sizes, int n_in,
                              void* d_out, int out_size, void* d_ws, size_t ws_size,
                              hipStream_t stream) {
  const float* x   = (const float*)d_in[0];
  const float* W1  = (const float*)d_in[1];
  const float* b1  = (const float*)d_in[2];
  const float* g1  = (const float*)d_in[3];
  const float* be1 = (const float*)d_in[4];
  const float* W2  = (const float*)d_in[5];
  const float* b2  = (const float*)d_in[6];
  const float* g2  = (const float*)d_in[7];
  const float* be2 = (const float*)d_in[8];
  const float* W3  = (const float*)d_in[9];
  const float* b3  = (const float*)d_in[10];

  const int B = 32768, H = 2048, DOUT = 1536;

  // ---- workspace layout (chunked) ----
  // persistent weights: W1t 262,144 + W2t 8,388,608 + W3t 6,291,456 = 14,942,208 B
  // per chunk of Bc rows: xt 128*Bc + h2 4096*Bc + max(h1 4096*Bc, params 6144*Bc)
  const size_t WEIGHTS = 14942208;
  int Bc = 1024;
  {
    const int cand[5] = {32768, 16384, 8192, 4096, 2048};
    for (int c = 0; c < 5; c++) {
      size_t need = WEIGHTS + (size_t)10368 * cand[c];
      if (need <= ws_size) { Bc = cand[c]; break; }
    }
  }
  char* ws = (char*)d_ws;
  unsigned short* W1t = (unsigned short*)(ws + 0);
  unsigned short* W2t = (unsigned short*)(ws + 262144);
  unsigned short* W3t = (unsigned short*)(ws + 8650752);
  unsigned short* xt  = (unsigned short*)(ws + WEIGHTS);
  unsigned short* h2  = (unsigned short*)(ws + WEIGHTS + (size_t)128 * Bc);
  char*           uni = ws + WEIGHTS + (size_t)(128 + 4096) * Bc;
  unsigned short* h1  = (unsigned short*)uni;
  float*      params  = (float*)uni; // aliases h1 (dead when GEMM3 writes)

  float* out = (float*)d_out;
  float* logdet = out + (size_t)B * 128;

  transpose_cast_kernel<<<dim3(64, 2), dim3(256), 0, stream>>>(W1, W1t, 64, H);
  transpose_cast_kernel<<<dim3(64, 64), dim3(256), 0, stream>>>(W2, W2t, H, H);
  transpose_cast_kernel<<<dim3(48, 64), dim3(256), 0, stream>>>(W3, W3t, H, DOUT);

  for (int r0 = 0; r0 < B; r0 += Bc) {
    cast_x_kernel<<<dim3(Bc / 4), dim3(256), 0, stream>>>(x + (size_t)r0 * 128, xt);
    // GEMM1: K=64 -> 128^2 kernel (memory-bound)
    gemm_bt_kernel<1><<<dim3((Bc / 128) * 16), dim3(256), 0, stream>>>(
        xt, W1t, b1, g1, be1, (void*)h1, Bc, H, 64);
    // GEMM2/GEMM3: 256^2 B-carry snake + uniform 1-half-tile/phase staging
    gemm256_kernel<1><<<dim3((Bc / 256) * (H / 256)), dim3(512), 0, stream>>>(
        h1, W2t, b2, g2, be2, (void*)h2, Bc, H, H);
    gemm256_kernel<0><<<dim3((Bc / 256) * (DOUT / 256)), dim3(512), 0, stream>>>(
        h2, W3t, b3, b3, b3, (void*)params, Bc, DOUT, H);
    spline_kernel<<<dim3(Bc / 4), dim3(256), 0, stream>>>(
        x + (size_t)r0 * 128, params, out + (size_t)r0 * 128, logdet + r0);
  }
}

// Round 5
// 665.927 us; speedup vs baseline: 1.1701x; 1.0935x over previous
//
#include <hip/hip_runtime.h>
#include <stdint.h>

// ---------- types ----------
typedef __attribute__((ext_vector_type(8))) __bf16 bf16x8;
typedef __attribute__((ext_vector_type(4))) float f32x4;

#define MIN_WF 0.001f
#define MIN_HF 0.001f
#define MIN_DF 0.001f
#define BN_INV 0.99999500003749977f /* 1/sqrt(1+1e-5) */

// async global->LDS, 16B per lane; LDS dest = wave-uniform base + lane*16
#define GLL(g, l)                                                              \
  __builtin_amdgcn_global_load_lds(                                            \
      (const __attribute__((address_space(1))) void*)(g),                      \
      (__attribute__((address_space(3))) void*)(l), 16, 0, 0)

__device__ __forceinline__ unsigned short f2bf(float f) {
  union { float f; unsigned int u; } v; v.f = f;
  unsigned int r = v.u + 0x7FFFu + ((v.u >> 16) & 1u);
  return (unsigned short)(r >> 16);
}

// ---------- cast/select even columns of x -> bf16 (Bc x 64) ----------
__global__ void cast_x_kernel(const float* __restrict__ x, unsigned short* __restrict__ xt) {
  int gid = blockIdx.x * blockDim.x + threadIdx.x; // 0 .. Bc*64
  int b = gid >> 6, i = gid & 63;
  xt[gid] = f2bf(x[(size_t)b * 128 + 2 * i]);
}

// ---------- transpose + cast: W (KxN f32, row-major) -> Wt (NxK bf16) ----------
__global__ void transpose_cast_kernel(const float* __restrict__ W, unsigned short* __restrict__ Wt,
                                      int K, int N) {
  __shared__ float tile[32][33];
  int tx = threadIdx.x & 31, ty = threadIdx.x >> 5; // 256 threads: ty 0..7
  int n0 = blockIdx.x * 32, k0 = blockIdx.y * 32;
#pragma unroll
  for (int i = 0; i < 32; i += 8)
    tile[ty + i][tx] = W[(size_t)(k0 + ty + i) * N + n0 + tx];
  __syncthreads();
#pragma unroll
  for (int i = 0; i < 32; i += 8)
    Wt[(size_t)(n0 + ty + i) * K + k0 + tx] = f2bf(tile[tx][ty + i]);
}

// ---------- 128x128 GEMM (kept for GEMM1, K=64) ----------
template <int EPI>
__global__ __launch_bounds__(256) void gemm_bt_kernel(
    const unsigned short* __restrict__ A, const unsigned short* __restrict__ Bt,
    const float* __restrict__ bias, const float* __restrict__ gamma,
    const float* __restrict__ beta, void* __restrict__ Cout,
    int M, int N, int K) {
  constexpr int BM = 128, BN = 128, BK = 32;
  __shared__ __align__(16) unsigned short As[2][BM * BK]; // 16 KB
  __shared__ __align__(16) unsigned short Bs[2][BN * BK]; // 16 KB
  int tid = threadIdx.x;
  int lane = tid & 63;
  int wave = tid >> 6;
  int wm = (wave & 1) * 64;
  int wn = (wave >> 1) * 64;
  int ml = lane & 15;
  int kq = lane >> 4;

  int L = blockIdx.x;
  int Nt = N >> 7;
  int Mt = M >> 7;
  int mt, nt;
  int Mloc = Mt >> 3;
  if (((Mt & 7) == 0) && ((Mloc & 3) == 0) && ((Nt & 3) == 0)) {
    int xcd = L & 7;
    int i = L >> 3;
    int Ng = Nt >> 2;
    int ln = i & 3;
    int lm = (i >> 2) & 3;
    int g = i >> 4;
    int gn = g % Ng;
    int gm = g / Ng;
    mt = xcd * Mloc + gm * 4 + lm;
    nt = gn * 4 + ln;
  } else {
    mt = L / Nt;
    nt = L % Nt;
  }
  size_t bm = (size_t)mt * BM;
  size_t bn = (size_t)nt * BN;

  int sr = lane >> 2;
  int sc = ((((lane & 3) + 4) - ((lane >> 3) & 3)) & 3) * 8;
  const unsigned short* gA = A + (bm + wave * 32 + sr) * (size_t)K + sc;
  const unsigned short* gB = Bt + (bn + wave * 32 + sr) * (size_t)K + sc;
  unsigned short* lA0 = As[0] + wave * 32 * BK;
  unsigned short* lA1 = As[1] + wave * 32 * BK;
  unsigned short* lB0 = Bs[0] + wave * 32 * BK;
  unsigned short* lB1 = Bs[1] + wave * 32 * BK;

  int kqs = ((kq + ((ml >> 1) & 3)) & 3) * 8;

  f32x4 zero = {0.f, 0.f, 0.f, 0.f};
  f32x4 acc[4][4];
#pragma unroll
  for (int i = 0; i < 4; i++)
#pragma unroll
    for (int j = 0; j < 4; j++) acc[i][j] = zero;

  for (int kb = 0; kb < K; kb += 64) {
    GLL(gA + kb, lA0);
    GLL(gA + kb + (size_t)16 * K, lA0 + 16 * BK);
    GLL(gA + kb + 32, lA1);
    GLL(gA + kb + 32 + (size_t)16 * K, lA1 + 16 * BK);
    GLL(gB + kb, lB0);
    GLL(gB + kb + (size_t)16 * K, lB0 + 16 * BK);
    GLL(gB + kb + 32, lB1);
    GLL(gB + kb + 32 + (size_t)16 * K, lB1 + 16 * BK);
    __syncthreads();

#pragma unroll
    for (int p = 0; p < 2; p++) {
      bf16x8 af[4], bfr[4];
#pragma unroll
      for (int i = 0; i < 4; i++)
        af[i] = *(const bf16x8*)(&As[p][(wm + i * 16 + ml) * BK + kqs]);
#pragma unroll
      for (int j = 0; j < 4; j++)
        bfr[j] = *(const bf16x8*)(&Bs[p][(wn + j * 16 + ml) * BK + kqs]);
#pragma unroll
      for (int i = 0; i < 4; i++)
#pragma unroll
        for (int j = 0; j < 4; j++)
          acc[i][j] = __builtin_amdgcn_mfma_f32_16x16x32_bf16(af[i], bfr[j], acc[i][j], 0, 0, 0);
    }
    __syncthreads();
  }

#pragma unroll
  for (int i = 0; i < 4; i++) {
#pragma unroll
    for (int j = 0; j < 4; j++) {
      size_t col = bn + wn + j * 16 + ml;
      float bv = bias[col];
      float gv = (EPI == 1) ? gamma[col] * BN_INV : 0.f;
      float bev = (EPI == 1) ? beta[col] : 0.f;
#pragma unroll
      for (int r = 0; r < 4; r++) {
        size_t row = bm + wm + i * 16 + kq * 4 + r;
        float v = acc[i][j][r] + bv;
        if (EPI == 1) {
          v = fmaxf(v, 0.f);
          v = gv * v + bev;
          ((unsigned short*)Cout)[row * (size_t)N + col] = f2bf(v);
        } else {
          ((float*)Cout)[row * (size_t)N + col] = v;
        }
      }
    }
  }
}

// ---------- 256x256 GEMM, 16x16x32 MFMA, one barrier per K-tile ----------
// BM=BN=256, BK=64/tile, 8 waves (2M x 4N), wave tile 128x64, 128 KiB LDS.
// Structure per K-tile: issue ALL 8 GLLs for tile t+1 into buf[1-cur]
// (sched_barrier pins the issue early) -> compute 4 quadrants (B-carry
// order, 24 ds_read_b128 + 64 MFMA per wave) with NO internal barriers or
// waitcnt asm -- the compiler emits counted lgkmcnt and can software-
// pipeline reads against MFMAs; the 2 waves/SIMD drift apart inside the
// ~2500-cyc inter-barrier window so one wave's MFMA covers the other's
// LDS wait -> __syncthreads(). The implied vmcnt(0) drain is FREE: the
// loads it waits on were issued a full tile (~2500 cyc >> 900-cyc HBM
// latency) earlier. 2 barriers/iter (was 8). WAR is trivial: staging
// always targets the buffer not being read, and __syncthreads separates
// the last read of a buffer from its next overwrite.
// LDS chunk swizzle: phys16Bchunk = logical ^ (row&7), via pre-swizzled
// global source (linear GLL dest) + same XOR on ds_read address.
template <int EPI>
__global__ __launch_bounds__(512, 2) void gemm256_kernel(
    const unsigned short* __restrict__ A, const unsigned short* __restrict__ Bt,
    const float* __restrict__ bias, const float* __restrict__ gamma,
    const float* __restrict__ beta, void* __restrict__ Cout,
    int M, int N, int K) {
  __shared__ __align__(16) unsigned short As[2][256 * 64]; // 64 KB
  __shared__ __align__(16) unsigned short Bs[2][256 * 64]; // 64 KB

  const int tid = threadIdx.x;
  const int lane = tid & 63;
  const int wave = tid >> 6; // 0..7
  const int wm = wave >> 2;  // 0..1 (M half)
  const int wn = wave & 3;   // 0..3 (N quarter)
  const int ml = lane & 15;
  const int kq = lane >> 4;  // 0..3

  int L = blockIdx.x;
  int Nt = N >> 8, Mt = M >> 8;
  int mt, nt;
  if ((Mt & 7) == 0) {
    int xcd = L & 7, ii = L >> 3, Mloc = Mt >> 3;
    mt = xcd * Mloc + (ii % Mloc);
    nt = ii / Mloc;
  } else {
    mt = L / Nt;
    nt = L % Nt;
  }
  const size_t bm = (size_t)mt << 8;
  const size_t bn = (size_t)nt << 8;
  const size_t rK = (size_t)K;

  // staging: per GLL a wave covers 8 rows x 128 B; phys chunk l&7 holds
  // logical chunk (l&7)^(row&7)  (pre-swizzled global source, linear dest).
  const int srow = lane >> 3;
  const int schk = (lane & 7) ^ srow;
  const unsigned short* gA = A + (bm + wave * 8 + srow) * rK + schk * 8;
  const unsigned short* gB = Bt + (bn + wave * 8 + srow) * rK + schk * 8;

#define LDSA(b, h, c) (&As[b][((h) * 128 + (c) * 64 + wave * 8) * 64])
#define LDSB(b, h, c) (&Bs[b][((h) * 128 + (c) * 64 + wave * 8) * 64])
#define STA(b, h, gp, t)                                                       \
  GLL((gp) + (size_t)((h) * 128) * rK + (t) * 64, LDSA(b, h, 0));              \
  GLL((gp) + (size_t)((h) * 128 + 64) * rK + (t) * 64, LDSA(b, h, 1))
#define STB(b, h, gp, t)                                                       \
  GLL((gp) + (size_t)((h) * 128) * rK + (t) * 64, LDSB(b, h, 0));              \
  GLL((gp) + (size_t)((h) * 128 + 64) * rK + (t) * 64, LDSB(b, h, 1))
#define STAGE_TILE(b, gp_a, gp_b, t)                                           \
  STA(b, 0, gp_a, t);                                                          \
  STA(b, 1, gp_a, t);                                                          \
  STB(b, 0, gp_b, t);                                                          \
  STB(b, 1, gp_b, t)

  // fragment-read bases; row&7 == ml&7 for both A and B reads.
  const unsigned short* rA[2] = {&As[0][(wm * 128 + ml) * 64],
                                 &As[1][(wm * 128 + ml) * 64]};
  const unsigned short* rB[2] = {&Bs[0][(wn * 64 + ml) * 64],
                                 &Bs[1][(wn * 64 + ml) * 64]};
  const int ks0 = ((kq) ^ (ml & 7)) * 8;       // K-plane 0
  const int ks1 = ((4 + kq) ^ (ml & 7)) * 8;   // K-plane 1

  f32x4 acc[8][4];
  f32x4 zero = {0.f, 0.f, 0.f, 0.f};
#pragma unroll
  for (int i = 0; i < 8; i++)
#pragma unroll
    for (int j = 0; j < 4; j++) acc[i][j] = zero;

#define LD_A4(dst, b, ibase)                                                   \
  {                                                                            \
    _Pragma("unroll") for (int q = 0; q < 4; q++) {                            \
      dst[q][0] = *(const bf16x8*)(rA[b] + ((ibase) + q) * 1024 + ks0);        \
      dst[q][1] = *(const bf16x8*)(rA[b] + ((ibase) + q) * 1024 + ks1);        \
    }                                                                          \
  }
#define LD_B2(dst, b, jbase)                                                   \
  {                                                                            \
    _Pragma("unroll") for (int q = 0; q < 2; q++) {                            \
      dst[q][0] = *(const bf16x8*)(rB[b] + ((jbase) + q) * 1024 + ks0);        \
      dst[q][1] = *(const bf16x8*)(rB[b] + ((jbase) + q) * 1024 + ks1);        \
    }                                                                          \
  }
#define MMA16(aarr, barr, ig, jg)                                              \
  {                                                                            \
    _Pragma("unroll") for (int q = 0; q < 4; q++)                              \
        _Pragma("unroll") for (int r = 0; r < 2; r++) {                        \
      acc[(ig) * 4 + q][(jg) * 2 + r] = __builtin_amdgcn_mfma_f32_16x16x32_bf16( \
          aarr[q][0], barr[r][0], acc[(ig) * 4 + q][(jg) * 2 + r], 0, 0, 0);   \
      acc[(ig) * 4 + q][(jg) * 2 + r] = __builtin_amdgcn_mfma_f32_16x16x32_bf16( \
          aarr[q][1], barr[r][1], acc[(ig) * 4 + q][(jg) * 2 + r], 0, 0, 0);   \
    }                                                                          \
  }
// One K-tile: 4 quadrants, B-carry order (no re-reads), compiler-scheduled.
#define COMPUTE(b)                                                             \
  {                                                                            \
    bf16x8 a03[4][2], a47[4][2], b01[2][2], b23[2][2];                         \
    LD_A4(a03, b, 0);                                                          \
    LD_B2(b01, b, 0);                                                          \
    MMA16(a03, b01, 0, 0);                                                     \
    LD_B2(b23, b, 2);                                                          \
    MMA16(a03, b23, 0, 1);                                                     \
    LD_A4(a47, b, 4);                                                          \
    MMA16(a47, b23, 1, 1);                                                     \
    MMA16(a47, b01, 1, 0);                                                     \
  }

  const int NT = K >> 6; // 64-wide K tiles (even, >=2)

  // prologue: tile0 -> buf0; __syncthreads drains vmcnt(0) + barrier.
  STAGE_TILE(0, gA, gB, 0);
  __syncthreads();

  const unsigned short* gAi = gA;
  const unsigned short* gBi = gB;

  for (int t2 = 0; t2 < NT; t2 += 2) {
    const bool last = (t2 + 2 >= NT);
    // tile t2 (buf0); stage tile t2+1 -> buf1
    STAGE_TILE(1, gAi, gBi, 1);
    __builtin_amdgcn_sched_barrier(0);
    COMPUTE(0);
    __syncthreads();
    // tile t2+1 (buf1); stage tile t2+2 -> buf0
    if (!last) { STAGE_TILE(0, gAi, gBi, 2); }
    __builtin_amdgcn_sched_barrier(0);
    COMPUTE(1);
    __syncthreads();
    gAi += 128;
    gBi += 128;
  }

  // epilogue. D mapping: col = lane&15, row = (lane>>4)*4 + r
#pragma unroll
  for (int j = 0; j < 4; j++) {
    const size_t col = bn + wn * 64 + j * 16 + ml;
    const float bv = bias[col];
    const float gv = (EPI == 1) ? gamma[col] * BN_INV : 0.f;
    const float bev = (EPI == 1) ? beta[col] : 0.f;
#pragma unroll
    for (int i = 0; i < 8; i++) {
      const size_t row0 = bm + wm * 128 + i * 16 + kq * 4;
#pragma unroll
      for (int r = 0; r < 4; r++) {
        float v = acc[i][j][r] + bv;
        if (EPI == 1) {
          v = fmaxf(v, 0.f);
          v = gv * v + bev;
          ((unsigned short*)Cout)[(row0 + r) * (size_t)N + col] = f2bf(v);
        } else {
          ((float*)Cout)[(row0 + r) * (size_t)N + col] = v;
        }
      }
    }
  }
#undef COMPUTE
#undef MMA16
#undef LD_B2
#undef LD_A4
#undef STAGE_TILE
#undef STB
#undef STA
#undef LDSB
#undef LDSA
}

// ---------- RQ spline + output assembly + log_det ----------
__global__ void spline_kernel(const float* __restrict__ x, const float* __restrict__ params,
                              float* __restrict__ out, float* __restrict__ logdet) {
  int gid = blockIdx.x * blockDim.x + threadIdx.x; // 0 .. Bc*64
  int b = gid >> 6;
  int i = gid & 63;

  const float4* p = (const float4*)(params + (size_t)gid * 24);
  float4 q0 = p[0], q1 = p[1], q2 = p[2], q3 = p[3], q4 = p[4], q5 = p[5];
  float w[8] = {q0.x, q0.y, q0.z, q0.w, q1.x, q1.y, q1.z, q1.w};
  float hh[8] = {q2.x, q2.y, q2.z, q2.w, q3.x, q3.y, q3.z, q3.w};
  float dv[8] = {q4.x, q4.y, q4.z, q4.w, q5.x, q5.y, q5.z, q5.w};

  float mx = w[0];
#pragma unroll
  for (int k = 1; k < 8; k++) mx = fmaxf(mx, w[k]);
  float s = 0.f;
#pragma unroll
  for (int k = 0; k < 8; k++) { w[k] = expf(w[k] - mx); s += w[k]; }
  float sc = (1.f - 8.f * MIN_WF) / s;
  float cw[9];
  cw[0] = 0.f;
#pragma unroll
  for (int k = 0; k < 8; k++) cw[k + 1] = cw[k] + (MIN_WF + sc * w[k]);

  float mh = hh[0];
#pragma unroll
  for (int k = 1; k < 8; k++) mh = fmaxf(mh, hh[k]);
  float sh = 0.f;
#pragma unroll
  for (int k = 0; k < 8; k++) { hh[k] = expf(hh[k] - mh); sh += hh[k]; }
  float sch = (1.f - 8.f * MIN_HF) / sh;
  float ch[9];
  ch[0] = 0.f;
#pragma unroll
  for (int k = 0; k < 8; k++) ch[k + 1] = ch[k] + (MIN_HF + sch * hh[k]);

  float dk[9];
#pragma unroll
  for (int k = 0; k < 8; k++)
    dk[k] = MIN_DF + (fmaxf(dv[k], 0.f) + log1pf(expf(-fabsf(dv[k]))));
  dk[8] = MIN_DF;

  float xv = x[(size_t)b * 128 + 2 * i + 1]; // identity (odd) column

  int bi = 0;
#pragma unroll
  for (int k = 0; k < 8; k++) bi += (xv > cw[k]) ? 1 : 0;
  bi = (bi > 7) ? 7 : bi;

  float xl = 0.f, xr = 0.f, yl = 0.f, yr = 0.f, dl = 0.f, dr = 0.f;
#pragma unroll
  for (int k = 0; k < 8; k++) {
    if (k == bi) {
      xl = cw[k]; xr = cw[k + 1];
      yl = ch[k]; yr = ch[k + 1];
      dl = dk[k]; dr = dk[k + 1];
    }
  }

  float bw = xr - xl, bh = yr - yl;
  float t = (xv - xl) / bw;
  t = fminf(fmaxf(t, 0.f), 1.f);
  float num = bh * (dl * t * t + 2.f * t * (1.f - t));
  float den = dl + (dr - dl) * t;
  float o = yl + num / den;
  float ld = logf(bh) + 2.f * logf(2.f * t * (1.f - t) * dr + dl) - logf(den);

  float xe = x[(size_t)b * 128 + 2 * i]; // transform (even) column passthrough
  ((float2*)out)[(size_t)b * 64 + i] = make_float2(xe, o);

#pragma unroll
  for (int off = 32; off > 0; off >>= 1) ld += __shfl_xor(ld, off, 64);
  if ((threadIdx.x & 63) == 0) logdet[b] = ld;
}

// ---------- launch ----------
extern "C" void kernel_launch(void* const* d_in, const int* in_sizes, int n_in,
                              void* d_out, int out_size, void* d_ws, size_t ws_size,
                              hipStream_t stream) {
  const float* x   = (const float*)d_in[0];
  const float* W1  = (const float*)d_in[1];
  const float* b1  = (const float*)d_in[2];
  const float* g1  = (const float*)d_in[3];
  const float* be1 = (const float*)d_in[4];
  const float* W2  = (const float*)d_in[5];
  const float* b2  = (const float*)d_in[6];
  const float* g2  = (const float*)d_in[7];
  const float* be2 = (const float*)d_in[8];
  const float* W3  = (const float*)d_in[9];
  const float* b3  = (const float*)d_in[10];

  const int B = 32768, H = 2048, DOUT = 1536;

  // ---- workspace layout (chunked) ----
  // persistent weights: W1t 262,144 + W2t 8,388,608 + W3t 6,291,456 = 14,942,208 B
  // per chunk of Bc rows: xt 128*Bc + h2 4096*Bc + max(h1 4096*Bc, params 6144*Bc)
  const size_t WEIGHTS = 14942208;
  int Bc = 1024;
  {
    const int cand[5] = {32768, 16384, 8192, 4096, 2048};
    for (int c = 0; c < 5; c++) {
      size_t need = WEIGHTS + (size_t)10368 * cand[c];
      if (need <= ws_size) { Bc = cand[c]; break; }
    }
  }
  char* ws = (char*)d_ws;
  unsigned short* W1t = (unsigned short*)(ws + 0);
  unsigned short* W2t = (unsigned short*)(ws + 262144);
  unsigned short* W3t = (unsigned short*)(ws + 8650752);
  unsigned short* xt  = (unsigned short*)(ws + WEIGHTS);
  unsigned short* h2  = (unsigned short*)(ws + WEIGHTS + (size_t)128 * Bc);
  char*           uni = ws + WEIGHTS + (size_t)(128 + 4096) * Bc;
  unsigned short* h1  = (unsigned short*)uni;
  float*      params  = (float*)uni; // aliases h1 (dead when GEMM3 writes)

  float* out = (float*)d_out;
  float* logdet = out + (size_t)B * 128;

  transpose_cast_kernel<<<dim3(64, 2), dim3(256), 0, stream>>>(W1, W1t, 64, H);
  transpose_cast_kernel<<<dim3(64, 64), dim3(256), 0, stream>>>(W2, W2t, H, H);
  transpose_cast_kernel<<<dim3(48, 64), dim3(256), 0, stream>>>(W3, W3t, H, DOUT);

  for (int r0 = 0; r0 < B; r0 += Bc) {
    cast_x_kernel<<<dim3(Bc / 4), dim3(256), 0, stream>>>(x + (size_t)r0 * 128, xt);
    // GEMM1: K=64 -> 128^2 kernel (memory-bound)
    gemm_bt_kernel<1><<<dim3((Bc / 128) * 16), dim3(256), 0, stream>>>(
        xt, W1t, b1, g1, be1, (void*)h1, Bc, H, 64);
    // GEMM2/GEMM3: 256^2, one barrier per K-tile, full-tile prefetch
    gemm256_kernel<1><<<dim3((Bc / 256) * (H / 256)), dim3(512), 0, stream>>>(
        h1, W2t, b2, g2, be2, (void*)h2, Bc, H, H);
    gemm256_kernel<0><<<dim3((Bc / 256) * (DOUT / 256)), dim3(512), 0, stream>>>(
        h2, W3t, b3, b3, b3, (void*)params, Bc, DOUT, H);
    spline_kernel<<<dim3(Bc / 4), dim3(256), 0, stream>>>(
        x + (size_t)r0 * 128, params, out + (size_t)r0 * 128, logdet + r0);
  }
}